// Round 14
// baseline (173693.689 us; speedup 1.0000x reference)
//
#include <hip/hip_runtime.h>
#include <math.h>

// ---------------------------------------------------------------------------
// Persistent-kernel trainer for the 16384-step sequential MLP scan.
// R23 == R22 resubmitted (round-13 bench died to container/infra failure;
// audit clean; precedent R19->R20: clean resubmit passed and won -5.5%).
// R22: R21 (164.5k us) + wave0-localization of the d3/softmax/o2 pipeline.
//  1) s3 -> 8 regs/lane (col k), d3 -> rotating reg pair, b3/p3r -> regs.
//  2) o2 computed IN wave0 (8 wredf chains on in-register s3r*d3) ->
//     deletes barrier #7 + d3 LDS round-trip; Phase B = {P3 loads ->
//     stores/prefetch -> wave0 softmax+o2 (no barriers) -> 1 barrier -> q0}.
//  3) shadow barrier merged with P-wait barrier (poll before, reduce after).
// Barriers/step 10 -> 8. Sync protocol untouched.
// Base: 128WG x CW=8, s1a/s1b split, NBANK=8, P3B=8, AC 128B-padded.
// ---------------------------------------------------------------------------

#define NSTEP 16384
#define INDIM 1024
#define HID   1024
#define OUTD  64
#define LR    0.01f
#define EPSN  1e-8f

#define NWG   128
#define TPB   1024
#define CW    8
#define NBANK 8      // O1R banks
#define P3B   8      // P3 banks
#define CSTR  32     // counter stride in ints (128 B)

// workspace layout (float/int indices)
#define OFF_ARRIVE   0                         // 256 ints (init barrier)
#define OFF_RELEASE  512                       // 1 int
#define OFF_PCNT     1024                      // 16 counters, stride 32 ints
#define OFF_QCNT     2048                      // 16 counters, stride 32 ints
#define OFF_U        4096                      // HID floats
#define OFF_O1R      (OFF_U + HID)             // 2*NBANK*HID
#define OFF_P3       (OFF_O1R + 2*NBANK*HID)   // 2*P3B*OUTD
#define OFF_ACC      (OFF_P3 + 2*P3B*OUTD)     // 2*16*32 (banks padded to 128B)
#define OFF_SDOT     (OFF_ACC + 2*16*32)       // NSTEP
#define OFF_NORMX    (OFF_SDOT + NSTEP)        // NSTEP

// ACC slots: 0 m1, 1 m2, 2 m3, 3 dot_d2o2, 4 sum_o2sq, 5 sum_B2sq, 6 sum_a2sq

__device__ __forceinline__ float dload(const float* p){
  return __hip_atomic_load(p, __ATOMIC_RELAXED, __HIP_MEMORY_SCOPE_AGENT);
}
__device__ __forceinline__ void dstore(float* p, float v){
  __hip_atomic_store(p, v, __ATOMIC_RELAXED, __HIP_MEMORY_SCOPE_AGENT);
}
__device__ __forceinline__ int rload(const int* p){
  return __hip_atomic_load(p, __ATOMIC_RELAXED, __HIP_MEMORY_SCOPE_AGENT);
}
__device__ __forceinline__ void rstore(int* p, int v){
  __hip_atomic_store(p, v, __ATOMIC_RELAXED, __HIP_MEMORY_SCOPE_AGENT);
}
__device__ __forceinline__ void iadd(int* p){
  __hip_atomic_fetch_add(p, 1, __ATOMIC_RELAXED, __HIP_MEMORY_SCOPE_AGENT);
}
__device__ __forceinline__ float wredf(float v){
  #pragma unroll
  for (int m = 32; m; m >>= 1) v += __shfl_xor(v, m, 64);
  return v;
}
__device__ __forceinline__ float sigf(float z){ return 1.f/(1.f+__expf(-z)); }

__global__ __launch_bounds__(64) void bp_init(const float* __restrict__ x, float* wsf){
  const int t = blockIdx.x, tid = threadIdx.x;
  const float* xt = x + (size_t)t * INDIM;
  const float* xp = x + (size_t)(t > 0 ? t - 1 : 0) * INDIM;
  float sp = 0.f, nx = 0.f;
  #pragma unroll
  for (int e = 0; e < INDIM/64; e++){
    int i = tid + 64*e; float a = xt[i];
    nx += a*a; sp += a*xp[i];
  }
  sp = wredf(sp); nx = wredf(nx);
  if (tid == 0){ wsf[OFF_SDOT + t] = (t > 0) ? sp : 0.f; wsf[OFF_NORMX + t] = nx; }
  if (blockIdx.x == 0){
    int* wsi = (int*)wsf;
    for (int i = tid; i < 256; i += 64) wsi[OFF_ARRIVE + i] = 0;
    if (tid == 0) wsi[OFF_RELEASE] = 0;
    if (tid < 16){ wsi[OFF_PCNT + CSTR*tid] = 0; wsi[OFF_QCNT + CSTR*tid] = 0; }
    for (int i = tid; i < 2*NBANK*HID; i += 64) wsf[OFF_O1R + i] = 0.f;
    for (int i = tid; i < 2*P3B*OUTD;  i += 64) wsf[OFF_P3 + i]  = 0.f;
    for (int i = tid; i < 2*16*32;     i += 64) wsf[OFF_ACC + i] = 0.f;
    __syncthreads();
    if (tid == 0){
      float* acc1 = wsf + OFF_ACC + 16*32;   // parity-1, bank-0
      acc1[0] = 1.f; acc1[1] = 1.f; acc1[2] = 1.f; acc1[5] = 1.f;
    }
  }
}

__global__ __launch_bounds__(TPB) void bp_train(
    const float* __restrict__ xdat, const float* __restrict__ tgt,
    const float* __restrict__ w1g, const float* __restrict__ b1g,
    const float* __restrict__ w2g, const float* __restrict__ b2g,
    const float* __restrict__ w3g, const float* __restrict__ b3g,
    float* __restrict__ out, float* wsf)
{
  alignas(16) __shared__ float s1a[HID*4];    // w1 cols [wg*CW, wg*CW+4)
  alignas(16) __shared__ float s1b[HID*4];    // w1 cols [wg*CW+4, wg*CW+8)
  alignas(16) __shared__ float s2[CW*HID];    // w2 col-major: [j][i], 32KB
  alignas(16) __shared__ float a1b[2][HID];
  __shared__ float d1s[HID];
  __shared__ float b1s[HID];
  __shared__ float o1f[HID];
  __shared__ float o2l[CW], d2l[CW], b2l[CW];
  __shared__ float a2b[2][CW];
  __shared__ float ascr[256];

  const int tid = threadIdx.x;
  const int wg  = blockIdx.x;
  int*   arrive  = (int*)wsf + OFF_ARRIVE;
  int*   release = (int*)wsf + OFF_RELEASE;
  int*   PCNT    = (int*)wsf + OFF_PCNT;
  int*   QCNT    = (int*)wsf + OFF_QCNT;
  float* U   = wsf + OFF_U;
  float* O1R = wsf + OFF_O1R;
  float* P3  = wsf + OFF_P3;
  float* AC  = wsf + OFF_ACC;
  float* SD  = wsf + OFF_SDOT;
  float* NX  = wsf + OFF_NORMX;
  const int bank  = wg & 15;            // AC / counter bank (8 WGs each)
  const int obank = wg & (NBANK-1);     // O1R bank (16 WGs each)
  const int bank3 = wg & (P3B-1);       // P3 bank (16 WGs each)
  const int wid   = tid >> 6;

  // ---- wave0-resident state (lane k owns column k of w3, d3, b3, p3) ----
  float s3r0=0.f,s3r1=0.f,s3r2=0.f,s3r3=0.f,s3r4=0.f,s3r5=0.f,s3r6=0.f,s3r7=0.f;
  float d3cur = 0.f, d3prev = 0.f, b3r = 0.f, p3v = 0.f;

  // ---- load owned slices + replicas, zero state ----
  {
    const float4 wa = *reinterpret_cast<const float4*>(&w1g[(size_t)tid*HID + wg*CW]);
    const float4 wb = *reinterpret_cast<const float4*>(&w1g[(size_t)tid*HID + wg*CW + 4]);
    *reinterpret_cast<float4*>(&s1a[4*tid]) = wa;
    *reinterpret_cast<float4*>(&s1b[4*tid]) = wb;
  }
  for (int v = tid; v < CW*HID; v += TPB){
    int j = v & (CW-1); int i = v >> 3;
    s2[j*HID + i] = w2g[(size_t)i*HID + wg*CW + j];
  }
  if (tid < OUTD){
    b3r  = b3g[tid];
    s3r0 = w3g[(size_t)(wg*CW + 0)*OUTD + tid];
    s3r1 = w3g[(size_t)(wg*CW + 1)*OUTD + tid];
    s3r2 = w3g[(size_t)(wg*CW + 2)*OUTD + tid];
    s3r3 = w3g[(size_t)(wg*CW + 3)*OUTD + tid];
    s3r4 = w3g[(size_t)(wg*CW + 4)*OUTD + tid];
    s3r5 = w3g[(size_t)(wg*CW + 5)*OUTD + tid];
    s3r6 = w3g[(size_t)(wg*CW + 6)*OUTD + tid];
    s3r7 = w3g[(size_t)(wg*CW + 7)*OUTD + tid];
  }
  b1s[tid] = b1g[tid]; d1s[tid] = 0.f; o1f[tid] = 0.f; a1b[1][tid] = 0.f;
  if (tid < CW){
    b2l[tid] = b2g[wg*CW + tid];
    o2l[tid] = 0.f; d2l[tid] = 0.f; a2b[0][tid] = 0.f; a2b[1][tid] = 0.f;
  }
  __syncthreads();

  // x-row register pipeline: xr{0,1} hold rows of x; both start at row 0
  float xr0, xr1;
  // loop-carried prefetch registers (updated in the pre-Q window)
  float nxp, sdt, tv_pf, xnv_pre;

  // ---- publish u for step 0 ----
  {
    float xv = xdat[tid];
    xr0 = xv; xr1 = xv;
    float4 wa = *reinterpret_cast<const float4*>(&s1a[4*tid]);
    float4 wb = *reinterpret_cast<const float4*>(&s1b[4*tid]);
    float u_[CW];
    u_[0] = wredf(xv*wa.x); u_[1] = wredf(xv*wa.y);
    u_[2] = wredf(xv*wa.z); u_[3] = wredf(xv*wa.w);
    u_[4] = wredf(xv*wb.x); u_[5] = wredf(xv*wb.y);
    u_[6] = wredf(xv*wb.z); u_[7] = wredf(xv*wb.w);
    if ((tid & 63) == 0){
      #pragma unroll
      for (int c = 0; c < CW; c++) ascr[96 + wid*CW + c] = u_[c];
    }
    __syncthreads();
    if (tid < CW){
      float s = 0.f;
      #pragma unroll
      for (int w2_ = 0; w2_ < 16; w2_++) s += ascr[96 + w2_*CW + tid];
      dstore(&U[wg*CW + tid], s);
    }
  }
  // ---- prologue prefetch for t=0: trio (244..246) + sa1 partials (48..63) ----
  {
    nxp = NX[0]; sdt = SD[0];
    tv_pf = (tid < OUTD) ? tgt[tid] : 0.f;
    xnv_pre = xdat[(size_t)1*INDIM + tid];         // row 1 for shadow(0)
    if ((tid & 63) == 0) ascr[48 + wid] = 0.f;     // a1b[1] == 0 -> partials 0
    if (tid < 64){
      float v5 = wredf(b3r*b3r);                   // d3 = 0 at init
      if (tid == 0){ ascr[244]=0.f; ascr[245]=v5; ascr[246]=0.f; }
    }
  }
  // initial full funnel barrier (once)
  {
    asm volatile("s_waitcnt vmcnt(0) lgkmcnt(0)" ::: "memory");
    __syncthreads();
    if (tid == 0) rstore(&arrive[wg], 1);
    if (wg == 0){
      if (tid < NWG){ while (rload(&arrive[tid]) < 1) __builtin_amdgcn_s_sleep(1); }
      __syncthreads();
      if (tid == 0) rstore(release, 1);
    }
    if (tid == 0){ while (rload(release) < 1) __builtin_amdgcn_s_sleep(1); }
    __syncthreads();
    asm volatile("" ::: "memory");
  }

  for (int t = 0; t <= NSTEP; t++){
    const int p = t & 1, qq = p ^ 1;
    float* a1c = a1b[p];  float* a1p = a1b[qq];
    float* a2c = a2b[p];  float* a2p = a2b[qq];
    float a1cv = 0.f;     // stage-3 output kept for pre-Q sa1 partial

    // ================= Phase A =================
    // O1R + U first: they feed of0, the first consumer on the critical path
    float u0 = dload(&U[tid]);
    float r0 = 0.f;
    #pragma unroll
    for (int b = 0; b < NBANK; b++)
      r0 += dload(&O1R[(qq*NBANK + b)*HID + tid]);
    // AC staging: consumed after stage 2 (latency hidden under wredf chains)
    if (tid < 112){
      int s = tid >> 4, b = tid & 15;
      ascr[128 + s*16 + b] = dload(&AC[(qq*16 + b)*32 + s]);
    }

    float a1p0 = a1p[tid];
    float of0 = r0 * a1p0 * (1.f - a1p0);
    o1f[tid] = of0;

    // stage 2: per-wave partials (3 chains; sa1 + trio done pre-Q last step)
    {
      float v0 = d1s[tid]*of0;
      float v1 = of0*of0;
      float Ba = b1s[tid] - LR*of0;
      float v2 = Ba*Ba;
      v0 = wredf(v0); v1 = wredf(v1); v2 = wredf(v2);
      if ((tid & 63) == 0){
        ascr[0*16+wid]=v0; ascr[1*16+wid]=v1; ascr[2*16+wid]=v2;
      }
    }
    __syncthreads();
    if (tid < 64){
      if (tid < 4){
        float s = 0.f;
        #pragma unroll
        for (int w = 0; w < 16; w++) s += ascr[tid*16 + w];
        ascr[240 + tid] = s;
      } else if (tid >= 8 && tid < 15){
        int s_ = tid - 8;
        float s = 0.f;
        #pragma unroll
        for (int b = 0; b < 16; b++) s += ascr[128 + s_*16 + b];
        ascr[248 + s_] = s;
      }
    }
    __syncthreads();
    float dd  = ascr[240], so  = ascr[241], sb  = ascr[242], sa1 = ascr[243];
    float sd3 = ascr[244], sb3 = ascr[245], dp3 = ascr[246];
    float m1p = ascr[248], m2p = ascr[249], m3p = ascr[250], dq  = ascr[251];
    float soq = ascr[252], sB2 = ascr[253], sa2 = ascr[254];

    float n1  = fmaxf(sqrtf(fmaxf(m1p - 2.f*LR*dd  + LR*LR*nxp*so,  0.f)), EPSN);
    float nb1 = fmaxf(sqrtf(sb),  EPSN);
    float n2  = fmaxf(sqrtf(fmaxf(m2p - 2.f*LR*dq  + LR*LR*sa1*soq, 0.f)), EPSN);
    float nb2 = fmaxf(sqrtf(sB2), EPSN);
    float n3  = fmaxf(sqrtf(fmaxf(m3p - 2.f*LR*dp3 + LR*LR*sa2*sd3, 0.f)), EPSN);
    float nb3 = fmaxf(sqrtf(sb3), EPSN);
    float rn1 = 1.f/n1, rnb1 = 1.f/nb1, rn2 = 1.f/n2, rnb2 = 1.f/nb2;
    float rn3 = 1.f/n3, rnb3 = 1.f/nb3;

    // stage 3
    {
      float B0 = (b1s[tid] - LR*of0)*rnb1; b1s[tid] = B0;
      float dn0 = (u0 - LR*of0*sdt)*rn1;   d1s[tid] = dn0;
      a1cv = sigf(dn0 + B0);
      a1c[tid] = a1cv;
    }
    __syncthreads();

    // stage 4: fused W2 update + matvec (cols j and j+4 per thread)
    {
      int j = tid >> 8, l = tid & 255;
      float coefA = LR * o2l[j];
      float coefB = LR * o2l[j+4];
      float4 wa = *reinterpret_cast<float4*>(&s2[j*HID + 4*l]);
      float4 wb = *reinterpret_cast<float4*>(&s2[(j+4)*HID + 4*l]);
      float4 ap = *reinterpret_cast<const float4*>(&a1p[4*l]);
      float4 ac = *reinterpret_cast<const float4*>(&a1c[4*l]);
      wa.x = (wa.x - coefA*ap.x)*rn2;  wa.y = (wa.y - coefA*ap.y)*rn2;
      wa.z = (wa.z - coefA*ap.z)*rn2;  wa.w = (wa.w - coefA*ap.w)*rn2;
      wb.x = (wb.x - coefB*ap.x)*rn2;  wb.y = (wb.y - coefB*ap.y)*rn2;
      wb.z = (wb.z - coefB*ap.z)*rn2;  wb.w = (wb.w - coefB*ap.w)*rn2;
      *reinterpret_cast<float4*>(&s2[j*HID + 4*l])     = wa;
      *reinterpret_cast<float4*>(&s2[(j+4)*HID + 4*l]) = wb;
      float accA = ac.x*wa.x + ac.y*wa.y + ac.z*wa.z + ac.w*wa.w;
      float accB = ac.x*wb.x + ac.y*wb.y + ac.z*wb.z + ac.w*wb.w;
      float ms   = wa.x*wa.x + wa.y*wa.y + wa.z*wa.z + wa.w*wa.w
                 + wb.x*wb.x + wb.y*wb.y + wb.z*wb.z + wb.w*wb.w;
      accA = wredf(accA); accB = wredf(accB); ms = wredf(ms);
      if ((tid & 63) == 0){ ascr[wid] = accA; ascr[32 + wid] = accB; ascr[16 + wid] = ms; }
    }
    __syncthreads();
    if (tid < CW){
      float d2;
      if (tid < 4)
        d2 = ascr[4*tid] + ascr[4*tid+1] + ascr[4*tid+2] + ascr[4*tid+3];
      else {
        int b = 32 + 4*(tid-4);
        d2 = ascr[b] + ascr[b+1] + ascr[b+2] + ascr[b+3];
      }
      d2l[tid] = d2;
      float b2n = (b2l[tid] - LR*o2l[tid])*rnb2;
      b2l[tid] = b2n;
      a2c[tid] = sigf(d2 + b2n);
    }
    // wave0 program-order: tid<8 wrote a2c; tid==8 reads it (no barrier).
    if (tid == 8){
      float m2 = 0.f;
      #pragma unroll
      for (int w = 0; w < 16; w++) m2 += ascr[16 + w];
      unsafeAtomicAdd(&AC[(p*16 + bank)*32 + 1], m2);
      float s = 0.f;
      for (int j = 0; j < CW; j++){ float a = a2c[j]; s += a*a; }
      unsafeAtomicAdd(&AC[(p*16 + bank)*32 + 6], s);
    }

    // stage 5: fused W3 update + P3 publish (wave0, all-register w3 column)
    if (tid < OUTD){
      float d3k = d3prev;
      float contrib = 0.f, m3s = 0.f;
      { float w=s3r0; w=(w - LR*a2p[0]*d3k)*rn3; s3r0=w; contrib+=a2c[0]*w; m3s+=w*w; }
      { float w=s3r1; w=(w - LR*a2p[1]*d3k)*rn3; s3r1=w; contrib+=a2c[1]*w; m3s+=w*w; }
      { float w=s3r2; w=(w - LR*a2p[2]*d3k)*rn3; s3r2=w; contrib+=a2c[2]*w; m3s+=w*w; }
      { float w=s3r3; w=(w - LR*a2p[3]*d3k)*rn3; s3r3=w; contrib+=a2c[3]*w; m3s+=w*w; }
      { float w=s3r4; w=(w - LR*a2p[4]*d3k)*rn3; s3r4=w; contrib+=a2c[4]*w; m3s+=w*w; }
      { float w=s3r5; w=(w - LR*a2p[5]*d3k)*rn3; s3r5=w; contrib+=a2c[5]*w; m3s+=w*w; }
      { float w=s3r6; w=(w - LR*a2p[6]*d3k)*rn3; s3r6=w; contrib+=a2c[6]*w; m3s+=w*w; }
      { float w=s3r7; w=(w - LR*a2p[7]*d3k)*rn3; s3r7=w; contrib+=a2c[7]*w; m3s+=w*w; }
      unsafeAtomicAdd(&P3[(p*P3B + bank3)*OUTD + tid], contrib);
      m3s = wredf(m3s);
      if (tid == 0) unsafeAtomicAdd(&AC[(p*16 + bank)*32 + 2], m3s);
      b3r = (b3r - LR*d3k)*rnb3;
    }

    // ===== epilogue =====
    if (t == NSTEP){
      __syncthreads();
      const float* xl = xdat + (size_t)(NSTEP - 1)*INDIM;
      float xv = xl[tid];
      float c0 = LR*o1f[wg*CW+0], c1 = LR*o1f[wg*CW+1];
      float c2 = LR*o1f[wg*CW+2], c3 = LR*o1f[wg*CW+3];
      float c4 = LR*o1f[wg*CW+4], c5 = LR*o1f[wg*CW+5];
      float c6 = LR*o1f[wg*CW+6], c7 = LR*o1f[wg*CW+7];
      float4 wa = *reinterpret_cast<const float4*>(&s1a[4*tid]);
      float4 wb = *reinterpret_cast<const float4*>(&s1b[4*tid]);
      float4 ovA, ovB;
      ovA.x = (wa.x - c0*xv)*rn1; ovA.y = (wa.y - c1*xv)*rn1;
      ovA.z = (wa.z - c2*xv)*rn1; ovA.w = (wa.w - c3*xv)*rn1;
      ovB.x = (wb.x - c4*xv)*rn1; ovB.y = (wb.y - c5*xv)*rn1;
      ovB.z = (wb.z - c6*xv)*rn1; ovB.w = (wb.w - c7*xv)*rn1;
      *reinterpret_cast<float4*>(&out[(size_t)tid*HID + wg*CW])     = ovA;
      *reinterpret_cast<float4*>(&out[(size_t)tid*HID + wg*CW + 4]) = ovB;
      float4 o2a, o2b;
      o2a.x = s2[0*HID+tid]; o2a.y = s2[1*HID+tid];
      o2a.z = s2[2*HID+tid]; o2a.w = s2[3*HID+tid];
      o2b.x = s2[4*HID+tid]; o2b.y = s2[5*HID+tid];
      o2b.z = s2[6*HID+tid]; o2b.w = s2[7*HID+tid];
      *reinterpret_cast<float4*>(&out[(size_t)HID*HID + (size_t)tid*HID + wg*CW])     = o2a;
      *reinterpret_cast<float4*>(&out[(size_t)HID*HID + (size_t)tid*HID + wg*CW + 4]) = o2b;
      if (tid < OUTD){
        size_t base = (size_t)2*HID*HID;
        out[base + (size_t)(wg*CW + 0)*OUTD + tid] = s3r0;
        out[base + (size_t)(wg*CW + 1)*OUTD + tid] = s3r1;
        out[base + (size_t)(wg*CW + 2)*OUTD + tid] = s3r2;
        out[base + (size_t)(wg*CW + 3)*OUTD + tid] = s3r3;
        out[base + (size_t)(wg*CW + 4)*OUTD + tid] = s3r4;
        out[base + (size_t)(wg*CW + 5)*OUTD + tid] = s3r5;
        out[base + (size_t)(wg*CW + 6)*OUTD + tid] = s3r6;
        out[base + (size_t)(wg*CW + 7)*OUTD + tid] = s3r7;
      }
      break;
    }

    // ---- P-arrive: all P-side publishes are wave0's atomics ----
    if (wid == 0){
      asm volatile("s_waitcnt vmcnt(0) lgkmcnt(0)" ::: "memory");
      if (tid == 0) iadd(&PCNT[CSTR*bank]);
    }

    // ---- shadow (WG-local): fused W1 update + u_{t+1} partials + m1 ----
    {
      float xpv = (t & 1) ? xr0 : xr1;   // row t-1, loaded 2 steps ago
      float xnv = xnv_pre;               // row t+1, loaded in pre-Q window
      if (t & 1) xr0 = xnv; else xr1 = xnv;
      float c0 = LR*o1f[wg*CW+0], c1 = LR*o1f[wg*CW+1];
      float c2 = LR*o1f[wg*CW+2], c3 = LR*o1f[wg*CW+3];
      float c4 = LR*o1f[wg*CW+4], c5 = LR*o1f[wg*CW+5];
      float c6 = LR*o1f[wg*CW+6], c7 = LR*o1f[wg*CW+7];
      float4 wa = *reinterpret_cast<float4*>(&s1a[4*tid]);
      float4 wb = *reinterpret_cast<float4*>(&s1b[4*tid]);
      wa.x = (wa.x - c0*xpv)*rn1; wa.y = (wa.y - c1*xpv)*rn1;
      wa.z = (wa.z - c2*xpv)*rn1; wa.w = (wa.w - c3*xpv)*rn1;
      wb.x = (wb.x - c4*xpv)*rn1; wb.y = (wb.y - c5*xpv)*rn1;
      wb.z = (wb.z - c6*xpv)*rn1; wb.w = (wb.w - c7*xpv)*rn1;
      *reinterpret_cast<float4*>(&s1a[4*tid]) = wa;
      *reinterpret_cast<float4*>(&s1b[4*tid]) = wb;
      float m1s = wa.x*wa.x + wa.y*wa.y + wa.z*wa.z + wa.w*wa.w
                + wb.x*wb.x + wb.y*wb.y + wb.z*wb.z + wb.w*wb.w;
      float u_[CW];
      u_[0] = wredf(xnv*wa.x); u_[1] = wredf(xnv*wa.y);
      u_[2] = wredf(xnv*wa.z); u_[3] = wredf(xnv*wa.w);
      u_[4] = wredf(xnv*wb.x); u_[5] = wredf(xnv*wb.y);
      u_[6] = wredf(xnv*wb.z); u_[7] = wredf(xnv*wb.w);
      m1s = wredf(m1s);
      if ((tid & 63) == 0){
        #pragma unroll
        for (int c = 0; c < CW; c++) ascr[96 + wid*CW + c] = u_[c];
        ascr[224 + wid] = m1s;
      }
    }

    // ---- P-poll merged with shadow barrier (one barrier serves both) ----
    {
      const int ptgt = (NWG/16)*(t+1);
      if (tid < 16){
        while (rload(&PCNT[CSTR*tid]) < ptgt) __builtin_amdgcn_s_sleep(1);
      }
      __syncthreads();
      asm volatile("" ::: "memory");
    }
    float u_pub = 0.f;
    if (tid < CW){
      float s = 0.f;
      #pragma unroll
      for (int w2_ = 0; w2_ < 16; w2_++) s += ascr[96 + w2_*CW + tid];
      u_pub = s;
    }
    if (tid == 0){
      float m1 = 0.f;
      #pragma unroll
      for (int w2_ = 0; w2_ < 16; w2_++) m1 += ascr[224 + w2_];
      unsafeAtomicAdd(&AC[(p*16 + bank)*32 + 0], m1);
    }

    // ================= Phase B =================
    // P3 loads FIRST (8 MALL reads in flight), then independent work
    float p0v=0.f,p1v=0.f,p2v=0.f,p3vv=0.f,p4v=0.f,p5v=0.f,p6v=0.f,p7v=0.f;
    if (tid < OUTD){
      p0v = dload(&P3[(p*P3B + 0)*OUTD + tid]);
      p1v = dload(&P3[(p*P3B + 1)*OUTD + tid]);
      p2v = dload(&P3[(p*P3B + 2)*OUTD + tid]);
      p3vv= dload(&P3[(p*P3B + 3)*OUTD + tid]);
      p4v = dload(&P3[(p*P3B + 4)*OUTD + tid]);
      p5v = dload(&P3[(p*P3B + 5)*OUTD + tid]);
      p6v = dload(&P3[(p*P3B + 6)*OUTD + tid]);
      p7v = dload(&P3[(p*P3B + 7)*OUTD + tid]);
    }
    // early zeroing of next-parity accumulators (safe: P proven consumed)
    if (wg < NBANK) dstore(&O1R[(qq*NBANK + wg)*HID + tid], 0.f);
    if (wg < P3B && tid < OUTD) dstore(&P3[(qq*P3B + wg)*OUTD + tid], 0.f);
    if (wg < 16  && tid < 8)    dstore(&AC[(qq*16 + wg)*32 + tid], 0.f);
    if (tid < CW) dstore(&U[wg*CW + tid], u_pub);   // safe: all WGs past A stage1
    // prefetch s2 row (stable since stage 4) for the o1 partial
    float s2v0 = s2[0*HID+tid], s2v1 = s2[1*HID+tid];
    float s2v2 = s2[2*HID+tid], s2v3 = s2[3*HID+tid];
    float s2v4 = s2[4*HID+tid], s2v5 = s2[5*HID+tid];
    float s2v6 = s2[6*HID+tid], s2v7 = s2[7*HID+tid];

    // wave0: softmax + d3 + o2 (all in-register, no barriers)
    if (tid < OUTD){
      float s = ((p0v + p1v) + (p2v + p3vv)) + ((p4v + p5v) + (p6v + p7v));
      p3v = s;
      float a3 = sigf(s + b3r);
      float e3 = __expf(-a3);
      float es = wredf(e3);
      float net = e3 / es;
      d3cur = (tv_pf - net) * a3 * (1.f - a3);
      float w0 = wredf(s3r0*d3cur); float w1 = wredf(s3r1*d3cur);
      float w2 = wredf(s3r2*d3cur); float w3 = wredf(s3r3*d3cur);
      float w4 = wredf(s3r4*d3cur); float w5 = wredf(s3r5*d3cur);
      float w6 = wredf(s3r6*d3cur); float w7 = wredf(s3r7*d3cur);
      if (tid < 8){
        float wv = tid==0?w0: tid==1?w1: tid==2?w2: tid==3?w3:
                   tid==4?w4: tid==5?w5: tid==6?w6: w7;
        float a2v = a2c[tid];
        o2l[tid] = wv * a2v * (1.f - a2v);
      }
    }
    if (tid == 0){
      float dd2 = 0.f, so2 = 0.f, sB2n = 0.f;
      for (int j = 0; j < CW; j++){
        float ov = o2l[j];
        dd2 += d2l[j]*ov; so2 += ov*ov;
        float B = b2l[j] - LR*ov; sB2n += B*B;
      }
      unsafeAtomicAdd(&AC[(p*16 + bank)*32 + 3], dd2);
      unsafeAtomicAdd(&AC[(p*16 + bank)*32 + 4], so2);
      unsafeAtomicAdd(&AC[(p*16 + bank)*32 + 5], sB2n);
    }
    __syncthreads();   // o2l visible to all waves
    // o1 banked partial (wave-wide RMW)
    {
      float q0 = s2v0*o2l[0] + s2v1*o2l[1] + s2v2*o2l[2] + s2v3*o2l[3]
               + s2v4*o2l[4] + s2v5*o2l[5] + s2v6*o2l[6] + s2v7*o2l[7];
      unsafeAtomicAdd(&O1R[(p*NBANK + obank)*HID + tid], q0);
    }
    // ---- Q-arrive: block-wide drain, then bump padded counter ----
    asm volatile("s_waitcnt vmcnt(0) lgkmcnt(0)" ::: "memory");
    __syncthreads();
    if (tid == 0) iadd(&QCNT[CSTR*bank]);

    // ---- pre-Q window: Q-independent next-step work overlaps the hop ----
    {
      // cold hoists for t+1
      nxp = NX[t];                                   // NX[(t+1)-1]
      sdt = SD[(t + 1 < NSTEP) ? t + 1 : 0];
      tv_pf = (t + 1 < NSTEP && tid < OUTD) ? tgt[(size_t)(t+1)*OUTD + tid] : 0.f;
      // x row t+2 for shadow(t+1)
      xnv_pre = xdat[(size_t)(t + 2 < NSTEP ? t + 2 : NSTEP - 1)*INDIM + tid];
      // sa1 partials for t+1 (input: this step's stage-3 register output)
      float v3 = wredf(a1cv*a1cv);
      if ((tid & 63) == 0) ascr[48 + wid] = v3;
      // stage-2 trio for t+1 (inputs d3cur/b3r/p3v, all registers)
      if (tid < 64){
        float d3v = d3cur;
        float v4 = d3v*d3v;
        float B3 = b3r - LR*d3v; float v5 = B3*B3;
        float v6 = d3v * p3v;
        v4 = wredf(v4); v5 = wredf(v5); v6 = wredf(v6);
        if (tid == 0){ ascr[244]=v4; ascr[245]=v5; ascr[246]=v6; }
      }
      d3prev = d3cur;   // rotate for stage 5 of t+1
    }

    // ---- Q-wait ----
    {
      const int qtgt = (NWG/16)*(t+1);
      if (tid < 16){
        while (rload(&QCNT[CSTR*tid]) < qtgt) __builtin_amdgcn_s_sleep(1);
      }
      __syncthreads();
      asm volatile("" ::: "memory");
    }
  }
}

extern "C" void kernel_launch(void* const* d_in, const int* in_sizes, int n_in,
                              void* d_out, int out_size, void* d_ws, size_t ws_size,
                              hipStream_t stream){
  const float* x  = (const float*)d_in[0];
  const float* tg = (const float*)d_in[1];
  const float* w1 = (const float*)d_in[2];
  const float* b1 = (const float*)d_in[3];
  const float* w2 = (const float*)d_in[4];
  const float* b2 = (const float*)d_in[5];
  const float* w3 = (const float*)d_in[6];
  const float* b3 = (const float*)d_in[7];
  float* out = (float*)d_out;
  float* wsf = (float*)d_ws;
  hipLaunchKernelGGL(bp_init,  dim3(NSTEP), dim3(64),  0, stream, x, wsf);
  hipLaunchKernelGGL(bp_train, dim3(NWG),   dim3(TPB), 0, stream,
                     x, tg, w1, b1, w2, b2, w3, b3, out, wsf);
}

// Round 15
// 159226.831 us; speedup vs baseline: 1.0909x; 1.0909x over previous
//
#include <hip/hip_runtime.h>
#include <math.h>

// ---------------------------------------------------------------------------
// Persistent-kernel trainer for the 16384-step sequential MLP scan.
// R24: REVERT to R21 (164.5k us, best verified) + the one cheap piece of
// R22: shadow barrier merged with P-wait barrier (poll before the barrier,
// u_pub reduce + m1 add after). R22/R23's wave0-localized o2 REGRESSED
// (+5.6%): serializing 8 parallel wredf chains (8 waves) + softmax into
// wave0 added ~0.7us of dependent shuffle chain to Phase B's critical path
// -- more than the two deleted barriers saved. Lesson: barriers < serialized
// reductions. Everything else byte-identical to R21: 128WG x CW=8, s1a/s1b
// split, NBANK=8, P3B=8, AC 128B-padded, parallel 512-thread o2 wredf,
// pre-Q window (hoists + x-pipeline + sa1 + trio), bar#5 deleted (tid8 AC).
// ---------------------------------------------------------------------------

#define NSTEP 16384
#define INDIM 1024
#define HID   1024
#define OUTD  64
#define LR    0.01f
#define EPSN  1e-8f

#define NWG   128
#define TPB   1024
#define CW    8
#define NBANK 8      // O1R banks
#define P3B   8      // P3 banks
#define CSTR  32     // counter stride in ints (128 B)

// workspace layout (float/int indices)
#define OFF_ARRIVE   0                         // 256 ints (init barrier)
#define OFF_RELEASE  512                       // 1 int
#define OFF_PCNT     1024                      // 16 counters, stride 32 ints
#define OFF_QCNT     2048                      // 16 counters, stride 32 ints
#define OFF_U        4096                      // HID floats
#define OFF_O1R      (OFF_U + HID)             // 2*NBANK*HID
#define OFF_P3       (OFF_O1R + 2*NBANK*HID)   // 2*P3B*OUTD
#define OFF_ACC      (OFF_P3 + 2*P3B*OUTD)     // 2*16*32 (banks padded to 128B)
#define OFF_SDOT     (OFF_ACC + 2*16*32)       // NSTEP
#define OFF_NORMX    (OFF_SDOT + NSTEP)        // NSTEP

// ACC slots: 0 m1, 1 m2, 2 m3, 3 dot_d2o2, 4 sum_o2sq, 5 sum_B2sq, 6 sum_a2sq

__device__ __forceinline__ float dload(const float* p){
  return __hip_atomic_load(p, __ATOMIC_RELAXED, __HIP_MEMORY_SCOPE_AGENT);
}
__device__ __forceinline__ void dstore(float* p, float v){
  __hip_atomic_store(p, v, __ATOMIC_RELAXED, __HIP_MEMORY_SCOPE_AGENT);
}
__device__ __forceinline__ int rload(const int* p){
  return __hip_atomic_load(p, __ATOMIC_RELAXED, __HIP_MEMORY_SCOPE_AGENT);
}
__device__ __forceinline__ void rstore(int* p, int v){
  __hip_atomic_store(p, v, __ATOMIC_RELAXED, __HIP_MEMORY_SCOPE_AGENT);
}
__device__ __forceinline__ void iadd(int* p){
  __hip_atomic_fetch_add(p, 1, __ATOMIC_RELAXED, __HIP_MEMORY_SCOPE_AGENT);
}
__device__ __forceinline__ float wredf(float v){
  #pragma unroll
  for (int m = 32; m; m >>= 1) v += __shfl_xor(v, m, 64);
  return v;
}
__device__ __forceinline__ float sigf(float z){ return 1.f/(1.f+__expf(-z)); }

__global__ __launch_bounds__(64) void bp_init(const float* __restrict__ x, float* wsf){
  const int t = blockIdx.x, tid = threadIdx.x;
  const float* xt = x + (size_t)t * INDIM;
  const float* xp = x + (size_t)(t > 0 ? t - 1 : 0) * INDIM;
  float sp = 0.f, nx = 0.f;
  #pragma unroll
  for (int e = 0; e < INDIM/64; e++){
    int i = tid + 64*e; float a = xt[i];
    nx += a*a; sp += a*xp[i];
  }
  sp = wredf(sp); nx = wredf(nx);
  if (tid == 0){ wsf[OFF_SDOT + t] = (t > 0) ? sp : 0.f; wsf[OFF_NORMX + t] = nx; }
  if (blockIdx.x == 0){
    int* wsi = (int*)wsf;
    for (int i = tid; i < 256; i += 64) wsi[OFF_ARRIVE + i] = 0;
    if (tid == 0) wsi[OFF_RELEASE] = 0;
    if (tid < 16){ wsi[OFF_PCNT + CSTR*tid] = 0; wsi[OFF_QCNT + CSTR*tid] = 0; }
    for (int i = tid; i < 2*NBANK*HID; i += 64) wsf[OFF_O1R + i] = 0.f;
    for (int i = tid; i < 2*P3B*OUTD;  i += 64) wsf[OFF_P3 + i]  = 0.f;
    for (int i = tid; i < 2*16*32;     i += 64) wsf[OFF_ACC + i] = 0.f;
    __syncthreads();
    if (tid == 0){
      float* acc1 = wsf + OFF_ACC + 16*32;   // parity-1, bank-0
      acc1[0] = 1.f; acc1[1] = 1.f; acc1[2] = 1.f; acc1[5] = 1.f;
    }
  }
}

__global__ __launch_bounds__(TPB) void bp_train(
    const float* __restrict__ xdat, const float* __restrict__ tgt,
    const float* __restrict__ w1g, const float* __restrict__ b1g,
    const float* __restrict__ w2g, const float* __restrict__ b2g,
    const float* __restrict__ w3g, const float* __restrict__ b3g,
    float* __restrict__ out, float* wsf)
{
  alignas(16) __shared__ float s1a[HID*4];    // w1 cols [wg*CW, wg*CW+4)
  alignas(16) __shared__ float s1b[HID*4];    // w1 cols [wg*CW+4, wg*CW+8)
  alignas(16) __shared__ float s2[CW*HID];    // w2 col-major: [j][i], 32KB
  __shared__ float s3[CW*OUTD];               // w3 rows (8x64)
  alignas(16) __shared__ float a1b[2][HID];
  __shared__ float d1s[HID];
  __shared__ float b1s[HID];
  __shared__ float o1f[HID];
  __shared__ float d3b[2][OUTD];
  __shared__ float p3r[OUTD];
  __shared__ float b3s[OUTD];
  __shared__ float o2l[CW], d2l[CW], b2l[CW];
  __shared__ float a2b[2][CW];
  __shared__ float ascr[256];

  const int tid = threadIdx.x;
  const int wg  = blockIdx.x;
  int*   arrive  = (int*)wsf + OFF_ARRIVE;
  int*   release = (int*)wsf + OFF_RELEASE;
  int*   PCNT    = (int*)wsf + OFF_PCNT;
  int*   QCNT    = (int*)wsf + OFF_QCNT;
  float* U   = wsf + OFF_U;
  float* O1R = wsf + OFF_O1R;
  float* P3  = wsf + OFF_P3;
  float* AC  = wsf + OFF_ACC;
  float* SD  = wsf + OFF_SDOT;
  float* NX  = wsf + OFF_NORMX;
  const int bank  = wg & 15;            // AC / counter bank (8 WGs each)
  const int obank = wg & (NBANK-1);     // O1R bank (16 WGs each)
  const int bank3 = wg & (P3B-1);       // P3 bank (16 WGs each)
  const int wid   = tid >> 6;

  // ---- load owned slices + replicas, zero state ----
  {
    const float4 wa = *reinterpret_cast<const float4*>(&w1g[(size_t)tid*HID + wg*CW]);
    const float4 wb = *reinterpret_cast<const float4*>(&w1g[(size_t)tid*HID + wg*CW + 4]);
    *reinterpret_cast<float4*>(&s1a[4*tid]) = wa;
    *reinterpret_cast<float4*>(&s1b[4*tid]) = wb;
  }
  for (int v = tid; v < CW*HID; v += TPB){
    int j = v & (CW-1); int i = v >> 3;
    s2[j*HID + i] = w2g[(size_t)i*HID + wg*CW + j];
  }
  if (tid < CW*OUTD){
    int i = tid >> 6; int k = tid & 63;
    s3[tid] = w3g[(size_t)(wg*CW + i)*OUTD + k];
  }
  b1s[tid] = b1g[tid]; d1s[tid] = 0.f; o1f[tid] = 0.f; a1b[1][tid] = 0.f;
  if (tid < OUTD){ b3s[tid] = b3g[tid]; d3b[1][tid] = 0.f; p3r[tid] = 0.f; }
  if (tid < CW){
    b2l[tid] = b2g[wg*CW + tid];
    o2l[tid] = 0.f; d2l[tid] = 0.f; a2b[0][tid] = 0.f; a2b[1][tid] = 0.f;
  }
  __syncthreads();

  // x-row register pipeline: xr{0,1} hold rows of x; both start at row 0
  float xr0, xr1;
  // loop-carried prefetch registers (updated in the pre-Q window)
  float nxp, sdt, tv_pf, xnv_pre;

  // ---- publish u for step 0 ----
  {
    float xv = xdat[tid];
    xr0 = xv; xr1 = xv;
    float4 wa = *reinterpret_cast<const float4*>(&s1a[4*tid]);
    float4 wb = *reinterpret_cast<const float4*>(&s1b[4*tid]);
    float u_[CW];
    u_[0] = wredf(xv*wa.x); u_[1] = wredf(xv*wa.y);
    u_[2] = wredf(xv*wa.z); u_[3] = wredf(xv*wa.w);
    u_[4] = wredf(xv*wb.x); u_[5] = wredf(xv*wb.y);
    u_[6] = wredf(xv*wb.z); u_[7] = wredf(xv*wb.w);
    if ((tid & 63) == 0){
      #pragma unroll
      for (int c = 0; c < CW; c++) ascr[96 + wid*CW + c] = u_[c];
    }
    __syncthreads();
    if (tid < CW){
      float s = 0.f;
      #pragma unroll
      for (int w2_ = 0; w2_ < 16; w2_++) s += ascr[96 + w2_*CW + tid];
      dstore(&U[wg*CW + tid], s);
    }
  }
  // ---- prologue prefetch for t=0: trio (244..246) + sa1 partials (48..63) ----
  {
    nxp = NX[0]; sdt = SD[0];
    tv_pf = (tid < OUTD) ? tgt[tid] : 0.f;
    xnv_pre = xdat[(size_t)1*INDIM + tid];         // row 1 for shadow(0)
    if ((tid & 63) == 0) ascr[48 + wid] = 0.f;     // a1b[1] == 0 -> partials 0
    if (tid < 64){
      float d3v = d3b[1][tid];                      // zeros at init
      float v4 = d3v*d3v;
      float B3 = b3s[tid] - LR*d3v; float v5 = B3*B3;
      float v6 = d3v * p3r[tid];
      v4 = wredf(v4); v5 = wredf(v5); v6 = wredf(v6);
      if (tid == 0){ ascr[244]=v4; ascr[245]=v5; ascr[246]=v6; }
    }
  }
  // initial full funnel barrier (once)
  {
    asm volatile("s_waitcnt vmcnt(0) lgkmcnt(0)" ::: "memory");
    __syncthreads();
    if (tid == 0) rstore(&arrive[wg], 1);
    if (wg == 0){
      if (tid < NWG){ while (rload(&arrive[tid]) < 1) __builtin_amdgcn_s_sleep(1); }
      __syncthreads();
      if (tid == 0) rstore(release, 1);
    }
    if (tid == 0){ while (rload(release) < 1) __builtin_amdgcn_s_sleep(1); }
    __syncthreads();
    asm volatile("" ::: "memory");
  }

  for (int t = 0; t <= NSTEP; t++){
    const int p = t & 1, qq = p ^ 1;
    float* a1c = a1b[p];  float* a1p = a1b[qq];
    float* a2c = a2b[p];  float* a2p = a2b[qq];
    float* d3c = d3b[p];  float* d3p = d3b[qq];
    float a1cv = 0.f;     // stage-3 output kept for pre-Q sa1 partial

    // ================= Phase A =================
    // O1R + U first: they feed of0, the first consumer on the critical path
    float u0 = dload(&U[tid]);
    float r0 = 0.f;
    #pragma unroll
    for (int b = 0; b < NBANK; b++)
      r0 += dload(&O1R[(qq*NBANK + b)*HID + tid]);
    // AC staging: consumed after stage 2 (latency hidden under wredf chains)
    if (tid < 112){
      int s = tid >> 4, b = tid & 15;
      ascr[128 + s*16 + b] = dload(&AC[(qq*16 + b)*32 + s]);
    }

    float a1p0 = a1p[tid];
    float of0 = r0 * a1p0 * (1.f - a1p0);
    o1f[tid] = of0;

    // stage 2: per-wave partials (3 chains; sa1 + trio done pre-Q last step)
    {
      float v0 = d1s[tid]*of0;
      float v1 = of0*of0;
      float Ba = b1s[tid] - LR*of0;
      float v2 = Ba*Ba;
      v0 = wredf(v0); v1 = wredf(v1); v2 = wredf(v2);
      if ((tid & 63) == 0){
        ascr[0*16+wid]=v0; ascr[1*16+wid]=v1; ascr[2*16+wid]=v2;
      }
    }
    __syncthreads();
    if (tid < 64){
      if (tid < 4){
        float s = 0.f;
        #pragma unroll
        for (int w = 0; w < 16; w++) s += ascr[tid*16 + w];
        ascr[240 + tid] = s;
      } else if (tid >= 8 && tid < 15){
        int s_ = tid - 8;
        float s = 0.f;
        #pragma unroll
        for (int b = 0; b < 16; b++) s += ascr[128 + s_*16 + b];
        ascr[248 + s_] = s;
      }
    }
    __syncthreads();
    float dd  = ascr[240], so  = ascr[241], sb  = ascr[242], sa1 = ascr[243];
    float sd3 = ascr[244], sb3 = ascr[245], dp3 = ascr[246];
    float m1p = ascr[248], m2p = ascr[249], m3p = ascr[250], dq  = ascr[251];
    float soq = ascr[252], sB2 = ascr[253], sa2 = ascr[254];

    float n1  = fmaxf(sqrtf(fmaxf(m1p - 2.f*LR*dd  + LR*LR*nxp*so,  0.f)), EPSN);
    float nb1 = fmaxf(sqrtf(sb),  EPSN);
    float n2  = fmaxf(sqrtf(fmaxf(m2p - 2.f*LR*dq  + LR*LR*sa1*soq, 0.f)), EPSN);
    float nb2 = fmaxf(sqrtf(sB2), EPSN);
    float n3  = fmaxf(sqrtf(fmaxf(m3p - 2.f*LR*dp3 + LR*LR*sa2*sd3, 0.f)), EPSN);
    float nb3 = fmaxf(sqrtf(sb3), EPSN);
    float rn1 = 1.f/n1, rnb1 = 1.f/nb1, rn2 = 1.f/n2, rnb2 = 1.f/nb2;
    float rn3 = 1.f/n3, rnb3 = 1.f/nb3;

    // stage 3
    {
      float B0 = (b1s[tid] - LR*of0)*rnb1; b1s[tid] = B0;
      float dn0 = (u0 - LR*of0*sdt)*rn1;   d1s[tid] = dn0;
      a1cv = sigf(dn0 + B0);
      a1c[tid] = a1cv;
    }
    __syncthreads();

    // stage 4: fused W2 update + matvec (cols j and j+4 per thread)
    {
      int j = tid >> 8, l = tid & 255;
      float coefA = LR * o2l[j];
      float coefB = LR * o2l[j+4];
      float4 wa = *reinterpret_cast<float4*>(&s2[j*HID + 4*l]);
      float4 wb = *reinterpret_cast<float4*>(&s2[(j+4)*HID + 4*l]);
      float4 ap = *reinterpret_cast<const float4*>(&a1p[4*l]);
      float4 ac = *reinterpret_cast<const float4*>(&a1c[4*l]);
      wa.x = (wa.x - coefA*ap.x)*rn2;  wa.y = (wa.y - coefA*ap.y)*rn2;
      wa.z = (wa.z - coefA*ap.z)*rn2;  wa.w = (wa.w - coefA*ap.w)*rn2;
      wb.x = (wb.x - coefB*ap.x)*rn2;  wb.y = (wb.y - coefB*ap.y)*rn2;
      wb.z = (wb.z - coefB*ap.z)*rn2;  wb.w = (wb.w - coefB*ap.w)*rn2;
      *reinterpret_cast<float4*>(&s2[j*HID + 4*l])     = wa;
      *reinterpret_cast<float4*>(&s2[(j+4)*HID + 4*l]) = wb;
      float accA = ac.x*wa.x + ac.y*wa.y + ac.z*wa.z + ac.w*wa.w;
      float accB = ac.x*wb.x + ac.y*wb.y + ac.z*wb.z + ac.w*wb.w;
      float ms   = wa.x*wa.x + wa.y*wa.y + wa.z*wa.z + wa.w*wa.w
                 + wb.x*wb.x + wb.y*wb.y + wb.z*wb.z + wb.w*wb.w;
      accA = wredf(accA); accB = wredf(accB); ms = wredf(ms);
      if ((tid & 63) == 0){ ascr[wid] = accA; ascr[32 + wid] = accB; ascr[16 + wid] = ms; }
    }
    __syncthreads();
    if (tid < CW){
      float d2;
      if (tid < 4)
        d2 = ascr[4*tid] + ascr[4*tid+1] + ascr[4*tid+2] + ascr[4*tid+3];
      else {
        int b = 32 + 4*(tid-4);
        d2 = ascr[b] + ascr[b+1] + ascr[b+2] + ascr[b+3];
      }
      d2l[tid] = d2;
      float b2n = (b2l[tid] - LR*o2l[tid])*rnb2;
      b2l[tid] = b2n;
      a2c[tid] = sigf(d2 + b2n);
    }
    // wave0 program-order: tid<8 wrote a2c; tid==8 reads it (no barrier).
    // m2 reads ascr[16..31] (covered by the stage-4 barrier above).
    if (tid == 8){
      float m2 = 0.f;
      #pragma unroll
      for (int w = 0; w < 16; w++) m2 += ascr[16 + w];
      unsafeAtomicAdd(&AC[(p*16 + bank)*32 + 1], m2);
      float s = 0.f;
      for (int j = 0; j < CW; j++){ float a = a2c[j]; s += a*a; }
      unsafeAtomicAdd(&AC[(p*16 + bank)*32 + 6], s);
    }

    // stage 5: fused W3 update + P3 publish (wave0 only)
    if (tid < OUTD){
      int k = tid;
      float d3k = d3p[k];
      float contrib = 0.f, m3s = 0.f;
      #pragma unroll
      for (int i = 0; i < CW; i++){
        float w = s3[i*OUTD + k];
        w = (w - LR*a2p[i]*d3k)*rn3;
        s3[i*OUTD + k] = w;
        contrib += a2c[i]*w;
        m3s += w*w;
      }
      unsafeAtomicAdd(&P3[(p*P3B + bank3)*OUTD + k], contrib);
      m3s = wredf(m3s);
      if (k == 0) unsafeAtomicAdd(&AC[(p*16 + bank)*32 + 2], m3s);
      b3s[k] = (b3s[k] - LR*d3k)*rnb3;
    }

    // ===== epilogue =====
    if (t == NSTEP){
      __syncthreads();
      const float* xl = xdat + (size_t)(NSTEP - 1)*INDIM;
      float xv = xl[tid];
      float c0 = LR*o1f[wg*CW+0], c1 = LR*o1f[wg*CW+1];
      float c2 = LR*o1f[wg*CW+2], c3 = LR*o1f[wg*CW+3];
      float c4 = LR*o1f[wg*CW+4], c5 = LR*o1f[wg*CW+5];
      float c6 = LR*o1f[wg*CW+6], c7 = LR*o1f[wg*CW+7];
      float4 wa = *reinterpret_cast<const float4*>(&s1a[4*tid]);
      float4 wb = *reinterpret_cast<const float4*>(&s1b[4*tid]);
      float4 ovA, ovB;
      ovA.x = (wa.x - c0*xv)*rn1; ovA.y = (wa.y - c1*xv)*rn1;
      ovA.z = (wa.z - c2*xv)*rn1; ovA.w = (wa.w - c3*xv)*rn1;
      ovB.x = (wb.x - c4*xv)*rn1; ovB.y = (wb.y - c5*xv)*rn1;
      ovB.z = (wb.z - c6*xv)*rn1; ovB.w = (wb.w - c7*xv)*rn1;
      *reinterpret_cast<float4*>(&out[(size_t)tid*HID + wg*CW])     = ovA;
      *reinterpret_cast<float4*>(&out[(size_t)tid*HID + wg*CW + 4]) = ovB;
      float4 o2a, o2b;
      o2a.x = s2[0*HID+tid]; o2a.y = s2[1*HID+tid];
      o2a.z = s2[2*HID+tid]; o2a.w = s2[3*HID+tid];
      o2b.x = s2[4*HID+tid]; o2b.y = s2[5*HID+tid];
      o2b.z = s2[6*HID+tid]; o2b.w = s2[7*HID+tid];
      *reinterpret_cast<float4*>(&out[(size_t)HID*HID + (size_t)tid*HID + wg*CW])     = o2a;
      *reinterpret_cast<float4*>(&out[(size_t)HID*HID + (size_t)tid*HID + wg*CW + 4]) = o2b;
      if (tid < OUTD){
        #pragma unroll
        for (int i = 0; i < CW; i++)
          out[(size_t)2*HID*HID + (size_t)(wg*CW + i)*OUTD + tid] = s3[i*OUTD + tid];
      }
      break;
    }

    // ---- P-arrive: all P-side publishes are wave0's atomics ----
    if (wid == 0){
      asm volatile("s_waitcnt vmcnt(0) lgkmcnt(0)" ::: "memory");
      if (tid == 0) iadd(&PCNT[CSTR*bank]);
    }

    // ---- shadow (WG-local): fused W1 update + u_{t+1} partials + m1 ----
    {
      float xpv = (t & 1) ? xr0 : xr1;   // row t-1, loaded 2 steps ago
      float xnv = xnv_pre;               // row t+1, loaded in pre-Q window
      if (t & 1) xr0 = xnv; else xr1 = xnv;
      float c0 = LR*o1f[wg*CW+0], c1 = LR*o1f[wg*CW+1];
      float c2 = LR*o1f[wg*CW+2], c3 = LR*o1f[wg*CW+3];
      float c4 = LR*o1f[wg*CW+4], c5 = LR*o1f[wg*CW+5];
      float c6 = LR*o1f[wg*CW+6], c7 = LR*o1f[wg*CW+7];
      float4 wa = *reinterpret_cast<float4*>(&s1a[4*tid]);
      float4 wb = *reinterpret_cast<float4*>(&s1b[4*tid]);
      wa.x = (wa.x - c0*xpv)*rn1; wa.y = (wa.y - c1*xpv)*rn1;
      wa.z = (wa.z - c2*xpv)*rn1; wa.w = (wa.w - c3*xpv)*rn1;
      wb.x = (wb.x - c4*xpv)*rn1; wb.y = (wb.y - c5*xpv)*rn1;
      wb.z = (wb.z - c6*xpv)*rn1; wb.w = (wb.w - c7*xpv)*rn1;
      *reinterpret_cast<float4*>(&s1a[4*tid]) = wa;
      *reinterpret_cast<float4*>(&s1b[4*tid]) = wb;
      float m1s = wa.x*wa.x + wa.y*wa.y + wa.z*wa.z + wa.w*wa.w
                + wb.x*wb.x + wb.y*wb.y + wb.z*wb.z + wb.w*wb.w;
      float u_[CW];
      u_[0] = wredf(xnv*wa.x); u_[1] = wredf(xnv*wa.y);
      u_[2] = wredf(xnv*wa.z); u_[3] = wredf(xnv*wa.w);
      u_[4] = wredf(xnv*wb.x); u_[5] = wredf(xnv*wb.y);
      u_[6] = wredf(xnv*wb.z); u_[7] = wredf(xnv*wb.w);
      m1s = wredf(m1s);
      if ((tid & 63) == 0){
        #pragma unroll
        for (int c = 0; c < CW; c++) ascr[96 + wid*CW + c] = u_[c];
        ascr[224 + wid] = m1s;
      }
    }

    // ---- P-poll merged with shadow barrier (one barrier serves both) ----
    {
      const int ptgt = (NWG/16)*(t+1);
      if (tid < 16){
        while (rload(&PCNT[CSTR*tid]) < ptgt) __builtin_amdgcn_s_sleep(1);
      }
      __syncthreads();
      asm volatile("" ::: "memory");
    }
    float u_pub = 0.f;
    if (tid < CW){
      float s = 0.f;
      #pragma unroll
      for (int w2_ = 0; w2_ < 16; w2_++) s += ascr[96 + w2_*CW + tid];
      u_pub = s;
    }
    if (tid == 0){
      float m1 = 0.f;
      #pragma unroll
      for (int w2_ = 0; w2_ < 16; w2_++) m1 += ascr[224 + w2_];
      unsafeAtomicAdd(&AC[(p*16 + bank)*32 + 0], m1);
    }

    // ================= Phase B =================
    // P3 loads FIRST (8 MALL reads in flight), then independent work
    float p0v=0.f,p1v=0.f,p2v=0.f,p3v=0.f,p4v=0.f,p5v=0.f,p6v=0.f,p7v=0.f;
    if (tid < OUTD){
      p0v = dload(&P3[(p*P3B + 0)*OUTD + tid]);
      p1v = dload(&P3[(p*P3B + 1)*OUTD + tid]);
      p2v = dload(&P3[(p*P3B + 2)*OUTD + tid]);
      p3v = dload(&P3[(p*P3B + 3)*OUTD + tid]);
      p4v = dload(&P3[(p*P3B + 4)*OUTD + tid]);
      p5v = dload(&P3[(p*P3B + 5)*OUTD + tid]);
      p6v = dload(&P3[(p*P3B + 6)*OUTD + tid]);
      p7v = dload(&P3[(p*P3B + 7)*OUTD + tid]);
    }
    // early zeroing of next-parity accumulators (safe: P proven consumed)
    if (wg < NBANK) dstore(&O1R[(qq*NBANK + wg)*HID + tid], 0.f);
    if (wg < P3B && tid < OUTD) dstore(&P3[(qq*P3B + wg)*OUTD + tid], 0.f);
    if (wg < 16  && tid < 8)    dstore(&AC[(qq*16 + wg)*32 + tid], 0.f);
    if (tid < CW) dstore(&U[wg*CW + tid], u_pub);   // safe: all WGs past A stage1
    // prefetch s2 row (stable since stage 4) for the o1 partial
    float s2v0 = s2[0*HID+tid], s2v1 = s2[1*HID+tid];
    float s2v2 = s2[2*HID+tid], s2v3 = s2[3*HID+tid];
    float s2v4 = s2[4*HID+tid], s2v5 = s2[5*HID+tid];
    float s2v6 = s2[6*HID+tid], s2v7 = s2[7*HID+tid];

    if (tid < OUTD){
      float s = ((p0v + p1v) + (p2v + p3v)) + ((p4v + p5v) + (p6v + p7v));
      p3r[tid] = s;
      float a3 = sigf(s + b3s[tid]);
      float e3 = __expf(-a3);
      float es = wredf(e3);
      float net = e3 / es;
      d3c[tid] = (tv_pf - net) * a3 * (1.f - a3);
    }
    __syncthreads();
    if (tid < CW*OUTD){
      int i = tid >> 6, k = tid & 63;
      float v = wredf(s3[i*OUTD + k] * d3c[k]);
      if (k == 0){ float a2v = a2c[i]; o2l[i] = v * a2v * (1.f - a2v); }
    }
    __syncthreads();
    // o1 banked partial first (wave-wide RMW in flight), then scalar AC adds
    {
      float q0 = s2v0*o2l[0] + s2v1*o2l[1] + s2v2*o2l[2] + s2v3*o2l[3]
               + s2v4*o2l[4] + s2v5*o2l[5] + s2v6*o2l[6] + s2v7*o2l[7];
      unsafeAtomicAdd(&O1R[(p*NBANK + obank)*HID + tid], q0);
    }
    if (tid == 0){
      float dd2 = 0.f, so2 = 0.f, sB2n = 0.f;
      for (int j = 0; j < CW; j++){
        float ov = o2l[j];
        dd2 += d2l[j]*ov; so2 += ov*ov;
        float B = b2l[j] - LR*ov; sB2n += B*B;
      }
      unsafeAtomicAdd(&AC[(p*16 + bank)*32 + 3], dd2);
      unsafeAtomicAdd(&AC[(p*16 + bank)*32 + 4], so2);
      unsafeAtomicAdd(&AC[(p*16 + bank)*32 + 5], sB2n);
    }
    // ---- Q-arrive: block-wide drain, then bump padded counter ----
    asm volatile("s_waitcnt vmcnt(0) lgkmcnt(0)" ::: "memory");
    __syncthreads();
    if (tid == 0) iadd(&QCNT[CSTR*bank]);

    // ---- pre-Q window: Q-independent next-step work overlaps the hop ----
    {
      // cold hoists for t+1
      nxp = NX[t];                                   // NX[(t+1)-1]
      sdt = SD[(t + 1 < NSTEP) ? t + 1 : 0];
      tv_pf = (t + 1 < NSTEP && tid < OUTD) ? tgt[(size_t)(t+1)*OUTD + tid] : 0.f;
      // x row t+2 for shadow(t+1)
      xnv_pre = xdat[(size_t)(t + 2 < NSTEP ? t + 2 : NSTEP - 1)*INDIM + tid];
      // sa1 partials for t+1 (input: this step's stage-3 register output)
      float v3 = wredf(a1cv*a1cv);
      if ((tid & 63) == 0) ascr[48 + wid] = v3;
      // stage-2 trio for t+1 (inputs d3c/b3s/p3r all final in Phase B(t))
      if (tid < 64){
        float d3v = d3c[tid];
        float v4 = d3v*d3v;
        float B3 = b3s[tid] - LR*d3v; float v5 = B3*B3;
        float v6 = d3v * p3r[tid];
        v4 = wredf(v4); v5 = wredf(v5); v6 = wredf(v6);
        if (tid == 0){ ascr[244]=v4; ascr[245]=v5; ascr[246]=v6; }
      }
    }

    // ---- Q-wait ----
    {
      const int qtgt = (NWG/16)*(t+1);
      if (tid < 16){
        while (rload(&QCNT[CSTR*tid]) < qtgt) __builtin_amdgcn_s_sleep(1);
      }
      __syncthreads();
      asm volatile("" ::: "memory");
    }
  }
}

extern "C" void kernel_launch(void* const* d_in, const int* in_sizes, int n_in,
                              void* d_out, int out_size, void* d_ws, size_t ws_size,
                              hipStream_t stream){
  const float* x  = (const float*)d_in[0];
  const float* tg = (const float*)d_in[1];
  const float* w1 = (const float*)d_in[2];
  const float* b1 = (const float*)d_in[3];
  const float* w2 = (const float*)d_in[4];
  const float* b2 = (const float*)d_in[5];
  const float* w3 = (const float*)d_in[6];
  const float* b3 = (const float*)d_in[7];
  float* out = (float*)d_out;
  float* wsf = (float*)d_ws;
  hipLaunchKernelGGL(bp_init,  dim3(NSTEP), dim3(64),  0, stream, x, wsf);
  hipLaunchKernelGGL(bp_train, dim3(NWG),   dim3(TPB), 0, stream,
                     x, tg, w1, b1, w2, b2, w3, b3, out, wsf);
}

// Round 16
// 158801.489 us; speedup vs baseline: 1.0938x; 1.0027x over previous
//
#include <hip/hip_runtime.h>
#include <math.h>

// ---------------------------------------------------------------------------
// Persistent-kernel trainer for the 16384-step sequential MLP scan.
// R25: R24 (159.2k us) + softmax REPLICATION across the 8 o2-waves.
// R23 lesson: serializing the o2 reduction into wave0 loses (+5.6%); but its
// goal (kill softmax->o2 barrier + d3 LDS round-trip) works the other way:
// each thread tid<512 loads the 8 P3 banks for its k=tid&63 and computes the
// full softmax + d3 IN-REGISTER (each wave covers k=0..63 -> per-wave
// wredf(e3) exact). o2 wredf consumes register d3 -> barrier #6 deleted
// (9->8/step), d3b/p3r LDS deleted (stage5 uses wave0's d3prev register,
// pre-Q trio uses d3cur/p3reg). Redundant 8x P3 loads/exp are parallel
// across waves (off critical path). Base: 128WG x CW=8, s1a/s1b, NBANK=8,
// P3B=8, AC 128B-padded, merged P/shadow barrier, pre-Q window.
// ---------------------------------------------------------------------------

#define NSTEP 16384
#define INDIM 1024
#define HID   1024
#define OUTD  64
#define LR    0.01f
#define EPSN  1e-8f

#define NWG   128
#define TPB   1024
#define CW    8
#define NBANK 8      // O1R banks
#define P3B   8      // P3 banks
#define CSTR  32     // counter stride in ints (128 B)

// workspace layout (float/int indices)
#define OFF_ARRIVE   0                         // 256 ints (init barrier)
#define OFF_RELEASE  512                       // 1 int
#define OFF_PCNT     1024                      // 16 counters, stride 32 ints
#define OFF_QCNT     2048                      // 16 counters, stride 32 ints
#define OFF_U        4096                      // HID floats
#define OFF_O1R      (OFF_U + HID)             // 2*NBANK*HID
#define OFF_P3       (OFF_O1R + 2*NBANK*HID)   // 2*P3B*OUTD
#define OFF_ACC      (OFF_P3 + 2*P3B*OUTD)     // 2*16*32 (banks padded to 128B)
#define OFF_SDOT     (OFF_ACC + 2*16*32)       // NSTEP
#define OFF_NORMX    (OFF_SDOT + NSTEP)        // NSTEP

// ACC slots: 0 m1, 1 m2, 2 m3, 3 dot_d2o2, 4 sum_o2sq, 5 sum_B2sq, 6 sum_a2sq

__device__ __forceinline__ float dload(const float* p){
  return __hip_atomic_load(p, __ATOMIC_RELAXED, __HIP_MEMORY_SCOPE_AGENT);
}
__device__ __forceinline__ void dstore(float* p, float v){
  __hip_atomic_store(p, v, __ATOMIC_RELAXED, __HIP_MEMORY_SCOPE_AGENT);
}
__device__ __forceinline__ int rload(const int* p){
  return __hip_atomic_load(p, __ATOMIC_RELAXED, __HIP_MEMORY_SCOPE_AGENT);
}
__device__ __forceinline__ void rstore(int* p, int v){
  __hip_atomic_store(p, v, __ATOMIC_RELAXED, __HIP_MEMORY_SCOPE_AGENT);
}
__device__ __forceinline__ void iadd(int* p){
  __hip_atomic_fetch_add(p, 1, __ATOMIC_RELAXED, __HIP_MEMORY_SCOPE_AGENT);
}
__device__ __forceinline__ float wredf(float v){
  #pragma unroll
  for (int m = 32; m; m >>= 1) v += __shfl_xor(v, m, 64);
  return v;
}
__device__ __forceinline__ float sigf(float z){ return 1.f/(1.f+__expf(-z)); }

__global__ __launch_bounds__(64) void bp_init(const float* __restrict__ x, float* wsf){
  const int t = blockIdx.x, tid = threadIdx.x;
  const float* xt = x + (size_t)t * INDIM;
  const float* xp = x + (size_t)(t > 0 ? t - 1 : 0) * INDIM;
  float sp = 0.f, nx = 0.f;
  #pragma unroll
  for (int e = 0; e < INDIM/64; e++){
    int i = tid + 64*e; float a = xt[i];
    nx += a*a; sp += a*xp[i];
  }
  sp = wredf(sp); nx = wredf(nx);
  if (tid == 0){ wsf[OFF_SDOT + t] = (t > 0) ? sp : 0.f; wsf[OFF_NORMX + t] = nx; }
  if (blockIdx.x == 0){
    int* wsi = (int*)wsf;
    for (int i = tid; i < 256; i += 64) wsi[OFF_ARRIVE + i] = 0;
    if (tid == 0) wsi[OFF_RELEASE] = 0;
    if (tid < 16){ wsi[OFF_PCNT + CSTR*tid] = 0; wsi[OFF_QCNT + CSTR*tid] = 0; }
    for (int i = tid; i < 2*NBANK*HID; i += 64) wsf[OFF_O1R + i] = 0.f;
    for (int i = tid; i < 2*P3B*OUTD;  i += 64) wsf[OFF_P3 + i]  = 0.f;
    for (int i = tid; i < 2*16*32;     i += 64) wsf[OFF_ACC + i] = 0.f;
    __syncthreads();
    if (tid == 0){
      float* acc1 = wsf + OFF_ACC + 16*32;   // parity-1, bank-0
      acc1[0] = 1.f; acc1[1] = 1.f; acc1[2] = 1.f; acc1[5] = 1.f;
    }
  }
}

__global__ __launch_bounds__(TPB) void bp_train(
    const float* __restrict__ xdat, const float* __restrict__ tgt,
    const float* __restrict__ w1g, const float* __restrict__ b1g,
    const float* __restrict__ w2g, const float* __restrict__ b2g,
    const float* __restrict__ w3g, const float* __restrict__ b3g,
    float* __restrict__ out, float* wsf)
{
  alignas(16) __shared__ float s1a[HID*4];    // w1 cols [wg*CW, wg*CW+4)
  alignas(16) __shared__ float s1b[HID*4];    // w1 cols [wg*CW+4, wg*CW+8)
  alignas(16) __shared__ float s2[CW*HID];    // w2 col-major: [j][i], 32KB
  __shared__ float s3[CW*OUTD];               // w3 rows (8x64)
  alignas(16) __shared__ float a1b[2][HID];
  __shared__ float d1s[HID];
  __shared__ float b1s[HID];
  __shared__ float o1f[HID];
  __shared__ float b3s[OUTD];
  __shared__ float o2l[CW], d2l[CW], b2l[CW];
  __shared__ float a2b[2][CW];
  __shared__ float ascr[256];

  const int tid = threadIdx.x;
  const int wg  = blockIdx.x;
  int*   arrive  = (int*)wsf + OFF_ARRIVE;
  int*   release = (int*)wsf + OFF_RELEASE;
  int*   PCNT    = (int*)wsf + OFF_PCNT;
  int*   QCNT    = (int*)wsf + OFF_QCNT;
  float* U   = wsf + OFF_U;
  float* O1R = wsf + OFF_O1R;
  float* P3  = wsf + OFF_P3;
  float* AC  = wsf + OFF_ACC;
  float* SD  = wsf + OFF_SDOT;
  float* NX  = wsf + OFF_NORMX;
  const int bank  = wg & 15;            // AC / counter bank (8 WGs each)
  const int obank = wg & (NBANK-1);     // O1R bank (16 WGs each)
  const int bank3 = wg & (P3B-1);       // P3 bank (16 WGs each)
  const int wid   = tid >> 6;
  const int kk    = tid & 63;           // replicated softmax lane index

  // loop-carried softmax registers (valid for tid < CW*OUTD)
  float d3cur = 0.f, d3prev = 0.f, p3reg = 0.f;

  // ---- load owned slices + replicas, zero state ----
  {
    const float4 wa = *reinterpret_cast<const float4*>(&w1g[(size_t)tid*HID + wg*CW]);
    const float4 wb = *reinterpret_cast<const float4*>(&w1g[(size_t)tid*HID + wg*CW + 4]);
    *reinterpret_cast<float4*>(&s1a[4*tid]) = wa;
    *reinterpret_cast<float4*>(&s1b[4*tid]) = wb;
  }
  for (int v = tid; v < CW*HID; v += TPB){
    int j = v & (CW-1); int i = v >> 3;
    s2[j*HID + i] = w2g[(size_t)i*HID + wg*CW + j];
  }
  if (tid < CW*OUTD){
    int i = tid >> 6; int k = tid & 63;
    s3[tid] = w3g[(size_t)(wg*CW + i)*OUTD + k];
  }
  b1s[tid] = b1g[tid]; d1s[tid] = 0.f; o1f[tid] = 0.f; a1b[1][tid] = 0.f;
  if (tid < OUTD){ b3s[tid] = b3g[tid]; }
  if (tid < CW){
    b2l[tid] = b2g[wg*CW + tid];
    o2l[tid] = 0.f; d2l[tid] = 0.f; a2b[0][tid] = 0.f; a2b[1][tid] = 0.f;
  }
  __syncthreads();

  // x-row register pipeline: xr{0,1} hold rows of x; both start at row 0
  float xr0, xr1;
  // loop-carried prefetch registers (updated in the pre-Q window)
  float nxp, sdt, tv_pf, xnv_pre;

  // ---- publish u for step 0 ----
  {
    float xv = xdat[tid];
    xr0 = xv; xr1 = xv;
    float4 wa = *reinterpret_cast<const float4*>(&s1a[4*tid]);
    float4 wb = *reinterpret_cast<const float4*>(&s1b[4*tid]);
    float u_[CW];
    u_[0] = wredf(xv*wa.x); u_[1] = wredf(xv*wa.y);
    u_[2] = wredf(xv*wa.z); u_[3] = wredf(xv*wa.w);
    u_[4] = wredf(xv*wb.x); u_[5] = wredf(xv*wb.y);
    u_[6] = wredf(xv*wb.z); u_[7] = wredf(xv*wb.w);
    if ((tid & 63) == 0){
      #pragma unroll
      for (int c = 0; c < CW; c++) ascr[96 + wid*CW + c] = u_[c];
    }
    __syncthreads();
    if (tid < CW){
      float s = 0.f;
      #pragma unroll
      for (int w2_ = 0; w2_ < 16; w2_++) s += ascr[96 + w2_*CW + tid];
      dstore(&U[wg*CW + tid], s);
    }
  }
  // ---- prologue prefetch for t=0: trio (244..246) + sa1 partials (48..63) ----
  {
    nxp = NX[0]; sdt = SD[0];
    tv_pf = (tid < CW*OUTD) ? tgt[kk] : 0.f;
    xnv_pre = xdat[(size_t)1*INDIM + tid];         // row 1 for shadow(0)
    if ((tid & 63) == 0) ascr[48 + wid] = 0.f;     // a1b[1] == 0 -> partials 0
    if (tid < 64){
      float B3 = b3s[tid];                          // d3 = 0 at init
      float v5 = wredf(B3*B3);
      if (tid == 0){ ascr[244]=0.f; ascr[245]=v5; ascr[246]=0.f; }
    }
  }
  // initial full funnel barrier (once)
  {
    asm volatile("s_waitcnt vmcnt(0) lgkmcnt(0)" ::: "memory");
    __syncthreads();
    if (tid == 0) rstore(&arrive[wg], 1);
    if (wg == 0){
      if (tid < NWG){ while (rload(&arrive[tid]) < 1) __builtin_amdgcn_s_sleep(1); }
      __syncthreads();
      if (tid == 0) rstore(release, 1);
    }
    if (tid == 0){ while (rload(release) < 1) __builtin_amdgcn_s_sleep(1); }
    __syncthreads();
    asm volatile("" ::: "memory");
  }

  for (int t = 0; t <= NSTEP; t++){
    const int p = t & 1, qq = p ^ 1;
    float* a1c = a1b[p];  float* a1p = a1b[qq];
    float* a2c = a2b[p];  float* a2p = a2b[qq];
    float a1cv = 0.f;     // stage-3 output kept for pre-Q sa1 partial

    // ================= Phase A =================
    // O1R + U first: they feed of0, the first consumer on the critical path
    float u0 = dload(&U[tid]);
    float r0 = 0.f;
    #pragma unroll
    for (int b = 0; b < NBANK; b++)
      r0 += dload(&O1R[(qq*NBANK + b)*HID + tid]);
    // AC staging: consumed after stage 2 (latency hidden under wredf chains)
    if (tid < 112){
      int s = tid >> 4, b = tid & 15;
      ascr[128 + s*16 + b] = dload(&AC[(qq*16 + b)*32 + s]);
    }

    float a1p0 = a1p[tid];
    float of0 = r0 * a1p0 * (1.f - a1p0);
    o1f[tid] = of0;

    // stage 2: per-wave partials (3 chains; sa1 + trio done pre-Q last step)
    {
      float v0 = d1s[tid]*of0;
      float v1 = of0*of0;
      float Ba = b1s[tid] - LR*of0;
      float v2 = Ba*Ba;
      v0 = wredf(v0); v1 = wredf(v1); v2 = wredf(v2);
      if ((tid & 63) == 0){
        ascr[0*16+wid]=v0; ascr[1*16+wid]=v1; ascr[2*16+wid]=v2;
      }
    }
    __syncthreads();
    if (tid < 64){
      if (tid < 4){
        float s = 0.f;
        #pragma unroll
        for (int w = 0; w < 16; w++) s += ascr[tid*16 + w];
        ascr[240 + tid] = s;
      } else if (tid >= 8 && tid < 15){
        int s_ = tid - 8;
        float s = 0.f;
        #pragma unroll
        for (int b = 0; b < 16; b++) s += ascr[128 + s_*16 + b];
        ascr[248 + s_] = s;
      }
    }
    __syncthreads();
    float dd  = ascr[240], so  = ascr[241], sb  = ascr[242], sa1 = ascr[243];
    float sd3 = ascr[244], sb3 = ascr[245], dp3 = ascr[246];
    float m1p = ascr[248], m2p = ascr[249], m3p = ascr[250], dq  = ascr[251];
    float soq = ascr[252], sB2 = ascr[253], sa2 = ascr[254];

    float n1  = fmaxf(sqrtf(fmaxf(m1p - 2.f*LR*dd  + LR*LR*nxp*so,  0.f)), EPSN);
    float nb1 = fmaxf(sqrtf(sb),  EPSN);
    float n2  = fmaxf(sqrtf(fmaxf(m2p - 2.f*LR*dq  + LR*LR*sa1*soq, 0.f)), EPSN);
    float nb2 = fmaxf(sqrtf(sB2), EPSN);
    float n3  = fmaxf(sqrtf(fmaxf(m3p - 2.f*LR*dp3 + LR*LR*sa2*sd3, 0.f)), EPSN);
    float nb3 = fmaxf(sqrtf(sb3), EPSN);
    float rn1 = 1.f/n1, rnb1 = 1.f/nb1, rn2 = 1.f/n2, rnb2 = 1.f/nb2;
    float rn3 = 1.f/n3, rnb3 = 1.f/nb3;

    // stage 3
    {
      float B0 = (b1s[tid] - LR*of0)*rnb1; b1s[tid] = B0;
      float dn0 = (u0 - LR*of0*sdt)*rn1;   d1s[tid] = dn0;
      a1cv = sigf(dn0 + B0);
      a1c[tid] = a1cv;
    }
    __syncthreads();

    // stage 4: fused W2 update + matvec (cols j and j+4 per thread)
    {
      int j = tid >> 8, l = tid & 255;
      float coefA = LR * o2l[j];
      float coefB = LR * o2l[j+4];
      float4 wa = *reinterpret_cast<float4*>(&s2[j*HID + 4*l]);
      float4 wb = *reinterpret_cast<float4*>(&s2[(j+4)*HID + 4*l]);
      float4 ap = *reinterpret_cast<const float4*>(&a1p[4*l]);
      float4 ac = *reinterpret_cast<const float4*>(&a1c[4*l]);
      wa.x = (wa.x - coefA*ap.x)*rn2;  wa.y = (wa.y - coefA*ap.y)*rn2;
      wa.z = (wa.z - coefA*ap.z)*rn2;  wa.w = (wa.w - coefA*ap.w)*rn2;
      wb.x = (wb.x - coefB*ap.x)*rn2;  wb.y = (wb.y - coefB*ap.y)*rn2;
      wb.z = (wb.z - coefB*ap.z)*rn2;  wb.w = (wb.w - coefB*ap.w)*rn2;
      *reinterpret_cast<float4*>(&s2[j*HID + 4*l])     = wa;
      *reinterpret_cast<float4*>(&s2[(j+4)*HID + 4*l]) = wb;
      float accA = ac.x*wa.x + ac.y*wa.y + ac.z*wa.z + ac.w*wa.w;
      float accB = ac.x*wb.x + ac.y*wb.y + ac.z*wb.z + ac.w*wb.w;
      float ms   = wa.x*wa.x + wa.y*wa.y + wa.z*wa.z + wa.w*wa.w
                 + wb.x*wb.x + wb.y*wb.y + wb.z*wb.z + wb.w*wb.w;
      accA = wredf(accA); accB = wredf(accB); ms = wredf(ms);
      if ((tid & 63) == 0){ ascr[wid] = accA; ascr[32 + wid] = accB; ascr[16 + wid] = ms; }
    }
    __syncthreads();
    if (tid < CW){
      float d2;
      if (tid < 4)
        d2 = ascr[4*tid] + ascr[4*tid+1] + ascr[4*tid+2] + ascr[4*tid+3];
      else {
        int b = 32 + 4*(tid-4);
        d2 = ascr[b] + ascr[b+1] + ascr[b+2] + ascr[b+3];
      }
      d2l[tid] = d2;
      float b2n = (b2l[tid] - LR*o2l[tid])*rnb2;
      b2l[tid] = b2n;
      a2c[tid] = sigf(d2 + b2n);
    }
    // wave0 program-order: tid<8 wrote a2c; tid==8 reads it (no barrier).
    // m2 reads ascr[16..31] (covered by the stage-4 barrier above).
    if (tid == 8){
      float m2 = 0.f;
      #pragma unroll
      for (int w = 0; w < 16; w++) m2 += ascr[16 + w];
      unsafeAtomicAdd(&AC[(p*16 + bank)*32 + 1], m2);
      float s = 0.f;
      for (int j = 0; j < CW; j++){ float a = a2c[j]; s += a*a; }
      unsafeAtomicAdd(&AC[(p*16 + bank)*32 + 6], s);
    }

    // stage 5: fused W3 update + P3 publish (wave0; d3 from register)
    if (tid < OUTD){
      int k = tid;
      float d3k = d3prev;
      float contrib = 0.f, m3s = 0.f;
      #pragma unroll
      for (int i = 0; i < CW; i++){
        float w = s3[i*OUTD + k];
        w = (w - LR*a2p[i]*d3k)*rn3;
        s3[i*OUTD + k] = w;
        contrib += a2c[i]*w;
        m3s += w*w;
      }
      unsafeAtomicAdd(&P3[(p*P3B + bank3)*OUTD + k], contrib);
      m3s = wredf(m3s);
      if (k == 0) unsafeAtomicAdd(&AC[(p*16 + bank)*32 + 2], m3s);
      b3s[k] = (b3s[k] - LR*d3k)*rnb3;
    }

    // ===== epilogue =====
    if (t == NSTEP){
      __syncthreads();
      const float* xl = xdat + (size_t)(NSTEP - 1)*INDIM;
      float xv = xl[tid];
      float c0 = LR*o1f[wg*CW+0], c1 = LR*o1f[wg*CW+1];
      float c2 = LR*o1f[wg*CW+2], c3 = LR*o1f[wg*CW+3];
      float c4 = LR*o1f[wg*CW+4], c5 = LR*o1f[wg*CW+5];
      float c6 = LR*o1f[wg*CW+6], c7 = LR*o1f[wg*CW+7];
      float4 wa = *reinterpret_cast<const float4*>(&s1a[4*tid]);
      float4 wb = *reinterpret_cast<const float4*>(&s1b[4*tid]);
      float4 ovA, ovB;
      ovA.x = (wa.x - c0*xv)*rn1; ovA.y = (wa.y - c1*xv)*rn1;
      ovA.z = (wa.z - c2*xv)*rn1; ovA.w = (wa.w - c3*xv)*rn1;
      ovB.x = (wb.x - c4*xv)*rn1; ovB.y = (wb.y - c5*xv)*rn1;
      ovB.z = (wb.z - c6*xv)*rn1; ovB.w = (wb.w - c7*xv)*rn1;
      *reinterpret_cast<float4*>(&out[(size_t)tid*HID + wg*CW])     = ovA;
      *reinterpret_cast<float4*>(&out[(size_t)tid*HID + wg*CW + 4]) = ovB;
      float4 o2a, o2b;
      o2a.x = s2[0*HID+tid]; o2a.y = s2[1*HID+tid];
      o2a.z = s2[2*HID+tid]; o2a.w = s2[3*HID+tid];
      o2b.x = s2[4*HID+tid]; o2b.y = s2[5*HID+tid];
      o2b.z = s2[6*HID+tid]; o2b.w = s2[7*HID+tid];
      *reinterpret_cast<float4*>(&out[(size_t)HID*HID + (size_t)tid*HID + wg*CW])     = o2a;
      *reinterpret_cast<float4*>(&out[(size_t)HID*HID + (size_t)tid*HID + wg*CW + 4]) = o2b;
      if (tid < OUTD){
        #pragma unroll
        for (int i = 0; i < CW; i++)
          out[(size_t)2*HID*HID + (size_t)(wg*CW + i)*OUTD + tid] = s3[i*OUTD + tid];
      }
      break;
    }

    // ---- P-arrive: all P-side publishes are wave0's atomics ----
    if (wid == 0){
      asm volatile("s_waitcnt vmcnt(0) lgkmcnt(0)" ::: "memory");
      if (tid == 0) iadd(&PCNT[CSTR*bank]);
    }

    // ---- shadow (WG-local): fused W1 update + u_{t+1} partials + m1 ----
    {
      float xpv = (t & 1) ? xr0 : xr1;   // row t-1, loaded 2 steps ago
      float xnv = xnv_pre;               // row t+1, loaded in pre-Q window
      if (t & 1) xr0 = xnv; else xr1 = xnv;
      float c0 = LR*o1f[wg*CW+0], c1 = LR*o1f[wg*CW+1];
      float c2 = LR*o1f[wg*CW+2], c3 = LR*o1f[wg*CW+3];
      float c4 = LR*o1f[wg*CW+4], c5 = LR*o1f[wg*CW+5];
      float c6 = LR*o1f[wg*CW+6], c7 = LR*o1f[wg*CW+7];
      float4 wa = *reinterpret_cast<float4*>(&s1a[4*tid]);
      float4 wb = *reinterpret_cast<float4*>(&s1b[4*tid]);
      wa.x = (wa.x - c0*xpv)*rn1; wa.y = (wa.y - c1*xpv)*rn1;
      wa.z = (wa.z - c2*xpv)*rn1; wa.w = (wa.w - c3*xpv)*rn1;
      wb.x = (wb.x - c4*xpv)*rn1; wb.y = (wb.y - c5*xpv)*rn1;
      wb.z = (wb.z - c6*xpv)*rn1; wb.w = (wb.w - c7*xpv)*rn1;
      *reinterpret_cast<float4*>(&s1a[4*tid]) = wa;
      *reinterpret_cast<float4*>(&s1b[4*tid]) = wb;
      float m1s = wa.x*wa.x + wa.y*wa.y + wa.z*wa.z + wa.w*wa.w
                + wb.x*wb.x + wb.y*wb.y + wb.z*wb.z + wb.w*wb.w;
      float u_[CW];
      u_[0] = wredf(xnv*wa.x); u_[1] = wredf(xnv*wa.y);
      u_[2] = wredf(xnv*wa.z); u_[3] = wredf(xnv*wa.w);
      u_[4] = wredf(xnv*wb.x); u_[5] = wredf(xnv*wb.y);
      u_[6] = wredf(xnv*wb.z); u_[7] = wredf(xnv*wb.w);
      m1s = wredf(m1s);
      if ((tid & 63) == 0){
        #pragma unroll
        for (int c = 0; c < CW; c++) ascr[96 + wid*CW + c] = u_[c];
        ascr[224 + wid] = m1s;
      }
    }

    // ---- P-poll merged with shadow barrier (one barrier serves both) ----
    {
      const int ptgt = (NWG/16)*(t+1);
      if (tid < 16){
        while (rload(&PCNT[CSTR*tid]) < ptgt) __builtin_amdgcn_s_sleep(1);
      }
      __syncthreads();
      asm volatile("" ::: "memory");
    }
    float u_pub = 0.f;
    if (tid < CW){
      float s = 0.f;
      #pragma unroll
      for (int w2_ = 0; w2_ < 16; w2_++) s += ascr[96 + w2_*CW + tid];
      u_pub = s;
    }
    if (tid == 0){
      float m1 = 0.f;
      #pragma unroll
      for (int w2_ = 0; w2_ < 16; w2_++) m1 += ascr[224 + w2_];
      unsafeAtomicAdd(&AC[(p*16 + bank)*32 + 0], m1);
    }

    // ================= Phase B =================
    // P3 loads FIRST (8 MALL reads in flight, replicated to 8 o2-waves)
    float p0v=0.f,p1v=0.f,p2v=0.f,p3v=0.f,p4v=0.f,p5v=0.f,p6v=0.f,p7v=0.f;
    if (tid < CW*OUTD){
      p0v = dload(&P3[(p*P3B + 0)*OUTD + kk]);
      p1v = dload(&P3[(p*P3B + 1)*OUTD + kk]);
      p2v = dload(&P3[(p*P3B + 2)*OUTD + kk]);
      p3v = dload(&P3[(p*P3B + 3)*OUTD + kk]);
      p4v = dload(&P3[(p*P3B + 4)*OUTD + kk]);
      p5v = dload(&P3[(p*P3B + 5)*OUTD + kk]);
      p6v = dload(&P3[(p*P3B + 6)*OUTD + kk]);
      p7v = dload(&P3[(p*P3B + 7)*OUTD + kk]);
    }
    // early zeroing of next-parity accumulators (safe: P proven consumed)
    if (wg < NBANK) dstore(&O1R[(qq*NBANK + wg)*HID + tid], 0.f);
    if (wg < P3B && tid < OUTD) dstore(&P3[(qq*P3B + wg)*OUTD + tid], 0.f);
    if (wg < 16  && tid < 8)    dstore(&AC[(qq*16 + wg)*32 + tid], 0.f);
    if (tid < CW) dstore(&U[wg*CW + tid], u_pub);   // safe: all WGs past A stage1
    // prefetch s2 row (stable since stage 4) for the o1 partial
    float s2v0 = s2[0*HID+tid], s2v1 = s2[1*HID+tid];
    float s2v2 = s2[2*HID+tid], s2v3 = s2[3*HID+tid];
    float s2v4 = s2[4*HID+tid], s2v5 = s2[5*HID+tid];
    float s2v6 = s2[6*HID+tid], s2v7 = s2[7*HID+tid];

    // replicated softmax + d3 (register) + fused o2 wredf -- no barrier
    if (tid < CW*OUTD){
      float s = ((p0v + p1v) + (p2v + p3v)) + ((p4v + p5v) + (p6v + p7v));
      p3reg = s;
      float a3 = sigf(s + b3s[kk]);
      float e3 = __expf(-a3);
      float es = wredf(e3);              // exact per wave: lanes cover k=0..63
      float net = e3 / es;
      d3cur = (tv_pf - net) * a3 * (1.f - a3);
      int i = tid >> 6;
      float v = wredf(s3[i*OUTD + kk] * d3cur);
      if (kk == 0){ float a2v = a2c[i]; o2l[i] = v * a2v * (1.f - a2v); }
    }
    __syncthreads();
    // o1 banked partial first (wave-wide RMW in flight), then scalar AC adds
    {
      float q0 = s2v0*o2l[0] + s2v1*o2l[1] + s2v2*o2l[2] + s2v3*o2l[3]
               + s2v4*o2l[4] + s2v5*o2l[5] + s2v6*o2l[6] + s2v7*o2l[7];
      unsafeAtomicAdd(&O1R[(p*NBANK + obank)*HID + tid], q0);
    }
    if (tid == 0){
      float dd2 = 0.f, so2 = 0.f, sB2n = 0.f;
      for (int j = 0; j < CW; j++){
        float ov = o2l[j];
        dd2 += d2l[j]*ov; so2 += ov*ov;
        float B = b2l[j] - LR*ov; sB2n += B*B;
      }
      unsafeAtomicAdd(&AC[(p*16 + bank)*32 + 3], dd2);
      unsafeAtomicAdd(&AC[(p*16 + bank)*32 + 4], so2);
      unsafeAtomicAdd(&AC[(p*16 + bank)*32 + 5], sB2n);
    }
    // ---- Q-arrive: block-wide drain, then bump padded counter ----
    asm volatile("s_waitcnt vmcnt(0) lgkmcnt(0)" ::: "memory");
    __syncthreads();
    if (tid == 0) iadd(&QCNT[CSTR*bank]);

    // ---- pre-Q window: Q-independent next-step work overlaps the hop ----
    {
      // cold hoists for t+1
      nxp = NX[t];                                   // NX[(t+1)-1]
      sdt = SD[(t + 1 < NSTEP) ? t + 1 : 0];
      tv_pf = (t + 1 < NSTEP && tid < CW*OUTD) ? tgt[(size_t)(t+1)*OUTD + kk] : 0.f;
      // x row t+2 for shadow(t+1)
      xnv_pre = xdat[(size_t)(t + 2 < NSTEP ? t + 2 : NSTEP - 1)*INDIM + tid];
      // sa1 partials for t+1 (input: this step's stage-3 register output)
      float v3 = wredf(a1cv*a1cv);
      if ((tid & 63) == 0) ascr[48 + wid] = v3;
      // stage-2 trio for t+1 (inputs d3cur/b3s/p3reg; wave0 registers)
      if (tid < 64){
        float d3v = d3cur;
        float v4 = d3v*d3v;
        float B3 = b3s[tid] - LR*d3v; float v5 = B3*B3;
        float v6 = d3v * p3reg;
        v4 = wredf(v4); v5 = wredf(v5); v6 = wredf(v6);
        if (tid == 0){ ascr[244]=v4; ascr[245]=v5; ascr[246]=v6; }
      }
      d3prev = d3cur;   // rotate for stage 5 of t+1
    }

    // ---- Q-wait ----
    {
      const int qtgt = (NWG/16)*(t+1);
      if (tid < 16){
        while (rload(&QCNT[CSTR*tid]) < qtgt) __builtin_amdgcn_s_sleep(1);
      }
      __syncthreads();
      asm volatile("" ::: "memory");
    }
  }
}

extern "C" void kernel_launch(void* const* d_in, const int* in_sizes, int n_in,
                              void* d_out, int out_size, void* d_ws, size_t ws_size,
                              hipStream_t stream){
  const float* x  = (const float*)d_in[0];
  const float* tg = (const float*)d_in[1];
  const float* w1 = (const float*)d_in[2];
  const float* b1 = (const float*)d_in[3];
  const float* w2 = (const float*)d_in[4];
  const float* b2 = (const float*)d_in[5];
  const float* w3 = (const float*)d_in[6];
  const float* b3 = (const float*)d_in[7];
  float* out = (float*)d_out;
  float* wsf = (float*)d_ws;
  hipLaunchKernelGGL(bp_init,  dim3(NSTEP), dim3(64),  0, stream, x, wsf);
  hipLaunchKernelGGL(bp_train, dim3(NWG),   dim3(TPB), 0, stream,
                     x, tg, w1, b1, w2, b2, w3, b3, out, wsf);
}